// Round 2
// baseline (666.796 us; speedup 1.0000x reference)
//
#include <hip/hip_runtime.h>
#include <hip/hip_bf16.h>

#define BB 8
#define CC 256
#define CK 32
#define NN 4096

// Per-b scratch layout INSIDE d_out (each b owns 1048576 floats = CC*NN):
//   v : +0        (32*4096)   lives in the co<32 rows of out, overwritten last
//   f : +131072   (4096*32, token-major [n][k])
//   g : +262144
//   h : +393216
//   M : +524288   (4096)
//   Z : +528384   (4096)
// Total 532480 < 1048576. d_ws is NOT used (ws_size unknown -> assume nothing).
#define OBASE(b) ((size_t)(b) * 1048576)
#define OFF_V 0
#define OFF_F 131072
#define OFF_G 262144
#define OFF_H 393216
#define OFF_M 524288
#define OFF_Z 528384

// ---------------- projections: f/g/h = W @ x, stored token-major [b][n][CK] ----
__global__ __launch_bounds__(384) void proj_kernel(
    const float* __restrict__ x, const float* __restrict__ wf,
    const float* __restrict__ wg, const float* __restrict__ wh,
    float* __restrict__ sc)
{
  int tid = threadIdx.x;
  int blk = blockIdx.x;                 // B * 32 = 256 blocks
  int b = blk >> 5;
  int n = ((blk & 31) << 7) + (tid & 127);
  int wsel = __builtin_amdgcn_readfirstlane(tid >> 7);   // 0:f 1:g 2:h (wave-uniform)
  const float* w = (wsel == 0) ? wf : ((wsel == 1) ? wg : wh);
  size_t off    = (wsel == 0) ? OFF_F : ((wsel == 1) ? OFF_G : OFF_H);

  const float* xb = x + (size_t)b * CC * NN + n;
  float acc[CK];
  #pragma unroll
  for (int k = 0; k < CK; ++k) acc[k] = 0.f;

  #pragma unroll 4
  for (int c = 0; c < CC; ++c) {
    float xv = xb[(size_t)c * NN];      // coalesced over n
    #pragma unroll
    for (int k = 0; k < CK; ++k) acc[k] += w[k * CC + c] * xv;  // uniform -> s_load
  }
  float* o = sc + OBASE(b) + off + (size_t)n * CK;
  #pragma unroll
  for (int q = 0; q < 8; ++q) {
    float4 t = make_float4(acc[q*4], acc[q*4+1], acc[q*4+2], acc[q*4+3]);
    *(float4*)&o[q * 4] = t;
  }
}

// ---------------- pass B: per-row (n) softmax max M and denom Z over m --------
__global__ __launch_bounds__(256, 2) void passb_kernel(float* __restrict__ sc)
{
  __shared__ float flds[64 * 36];
  __shared__ float glds[64 * 36];
  int tid = threadIdx.x;
  int blk = blockIdx.x;                 // B * 64 = 512 blocks
  int b = blk >> 6;
  int n0 = (blk & 63) << 6;
  int ng = tid >> 4, mg = tid & 15;

  const float* fsrc = sc + OBASE(b) + OFF_F + (size_t)n0 * CK;
  for (int i = tid * 4; i < 64 * CK; i += 1024) {
    int r = i >> 5, c = i & 31;
    *(float4*)&flds[r * 36 + c] = *(const float4*)&fsrc[i];
  }
  __syncthreads();

  float4 fr[4][8];                      // this thread's 4 f-rows in registers
  #pragma unroll
  for (int i = 0; i < 4; ++i)
    #pragma unroll
    for (int q = 0; q < 8; ++q)
      fr[i][q] = *(float4*)&flds[(ng * 4 + i) * 36 + q * 4];

  float Mv[4], Zv[4];
  #pragma unroll
  for (int i = 0; i < 4; ++i) { Mv[i] = -3.0e38f; Zv[i] = 0.f; }

  for (int m0 = 0; m0 < NN; m0 += 64) {
    __syncthreads();
    const float* gsrc = sc + OBASE(b) + OFF_G + (size_t)m0 * CK;
    for (int i = tid * 4; i < 64 * CK; i += 1024) {
      int r = i >> 5, c = i & 31;
      *(float4*)&glds[r * 36 + c] = *(const float4*)&gsrc[i];
    }
    __syncthreads();

    float s[4][4];
    #pragma unroll
    for (int i = 0; i < 4; ++i)
      #pragma unroll
      for (int j = 0; j < 4; ++j) s[i][j] = 0.f;
    #pragma unroll
    for (int q = 0; q < 8; ++q) {
      float4 gv[4];
      #pragma unroll
      for (int j = 0; j < 4; ++j) gv[j] = *(float4*)&glds[(mg * 4 + j) * 36 + q * 4];
      #pragma unroll
      for (int i = 0; i < 4; ++i) {
        float4 fv = fr[i][q];
        #pragma unroll
        for (int j = 0; j < 4; ++j)
          s[i][j] += fv.x * gv[j].x + fv.y * gv[j].y + fv.z * gv[j].z + fv.w * gv[j].w;
      }
    }
    #pragma unroll
    for (int i = 0; i < 4; ++i) {
      float ml = fmaxf(fmaxf(s[i][0], s[i][1]), fmaxf(s[i][2], s[i][3]));
      float Mn = fmaxf(Mv[i], ml);
      float za = __expf(s[i][0] - Mn) + __expf(s[i][1] - Mn)
               + __expf(s[i][2] - Mn) + __expf(s[i][3] - Mn);
      Zv[i] = Zv[i] * __expf(Mv[i] - Mn) + za;
      Mv[i] = Mn;
    }
  }
  // merge the 16 m-lane partials (butterfly over mg)
  #pragma unroll
  for (int d = 1; d < 16; d <<= 1) {
    #pragma unroll
    for (int i = 0; i < 4; ++i) {
      float Mo = __shfl_xor(Mv[i], d);
      float Zo = __shfl_xor(Zv[i], d);
      float Mn = fmaxf(Mv[i], Mo);
      Zv[i] = Zv[i] * __expf(Mv[i] - Mn) + Zo * __expf(Mo - Mn);
      Mv[i] = Mn;
    }
  }
  if (mg == 0) {
    #pragma unroll
    for (int i = 0; i < 4; ++i) {
      sc[OBASE(b) + OFF_M + n0 + ng * 4 + i] = Mv[i];
      sc[OBASE(b) + OFF_Z + n0 + ng * 4 + i] = Zv[i];
    }
  }
}

// ------- pass C: v = (h/Z) @ exp(s - M), writes v tile into d_out's v region --
__global__ __launch_bounds__(256, 2) void passc_kernel(float* __restrict__ sc)
{
  __shared__ float flds[64 * 36];
  __shared__ float hlds[64 * 32];
  __shared__ float Plds[64 * 68];       // also reused as reduce scratch (4352 >= 4096)
  __shared__ float vlds[CK * 68];
  __shared__ float Ml[64];

  int tid = threadIdx.x;
  int blk = blockIdx.x;                 // B * 64 = 512 blocks
  int b = blk >> 6;
  int m0 = (blk & 63) << 6;
  int ng = tid >> 4, mg = tid & 15;               // s-phase roles
  int nh = tid >> 6, cg = (tid >> 3) & 7, mgr = tid & 7;  // PV-phase roles

  // this block's 4 g-columns (m fixed per block) in registers
  float4 gr[4][8];
  #pragma unroll
  for (int j = 0; j < 4; ++j) {
    const float* gsrc = sc + OBASE(b) + OFF_G + (size_t)(m0 + mg * 4 + j) * CK;
    #pragma unroll
    for (int q = 0; q < 8; ++q) gr[j][q] = *(const float4*)&gsrc[q * 4];
  }

  float acc[4][8];
  #pragma unroll
  for (int ci = 0; ci < 4; ++ci)
    #pragma unroll
    for (int mj = 0; mj < 8; ++mj) acc[ci][mj] = 0.f;

  for (int n0t = 0; n0t < NN; n0t += 64) {
    __syncthreads();                    // previous Plds consumers done
    const float* fsrc = sc + OBASE(b) + OFF_F + (size_t)n0t * CK;
    const float* hsrc = sc + OBASE(b) + OFF_H + (size_t)n0t * CK;
    const float* Zsrc = sc + OBASE(b) + OFF_Z + n0t;
    for (int i = tid * 4; i < 64 * CK; i += 1024) {
      int r = i >> 5, c = i & 31;
      *(float4*)&flds[r * 36 + c] = *(const float4*)&fsrc[i];
      float4 hv = *(const float4*)&hsrc[i];
      float zi = 1.0f / Zsrc[r];        // Z >= ~1 always
      hv.x *= zi; hv.y *= zi; hv.z *= zi; hv.w *= zi;
      *(float4*)&hlds[r * 32 + c] = hv;
    }
    if (tid < 64) Ml[tid] = sc[OBASE(b) + OFF_M + n0t + tid];
    __syncthreads();

    // s-tile + exp -> Plds
    float s[4][4];
    #pragma unroll
    for (int i = 0; i < 4; ++i)
      #pragma unroll
      for (int j = 0; j < 4; ++j) s[i][j] = 0.f;
    #pragma unroll
    for (int q = 0; q < 8; ++q) {
      float4 fv[4];
      #pragma unroll
      for (int i = 0; i < 4; ++i) fv[i] = *(float4*)&flds[(ng * 4 + i) * 36 + q * 4];
      #pragma unroll
      for (int i = 0; i < 4; ++i)
        #pragma unroll
        for (int j = 0; j < 4; ++j)
          s[i][j] += fv[i].x * gr[j][q].x + fv[i].y * gr[j][q].y
                   + fv[i].z * gr[j][q].z + fv[i].w * gr[j][q].w;
    }
    #pragma unroll
    for (int i = 0; i < 4; ++i) {
      float mrow = Ml[ng * 4 + i];
      float4 p;
      p.x = __expf(s[i][0] - mrow);
      p.y = __expf(s[i][1] - mrow);
      p.z = __expf(s[i][2] - mrow);
      p.w = __expf(s[i][3] - mrow);
      *(float4*)&Plds[(ng * 4 + i) * 68 + mg * 4] = p;
    }
    __syncthreads();

    // PV: acc[c-tile][m-tile] += h' * P, n split over the 4 waves
    #pragma unroll
    for (int nn = 0; nn < 16; ++nn) {
      int n = nh * 16 + nn;
      float4 hv = *(float4*)&hlds[n * 32 + cg * 4];
      float4 p0 = *(float4*)&Plds[n * 68 + mgr * 8];
      float4 p1 = *(float4*)&Plds[n * 68 + mgr * 8 + 4];
      float pv[8] = {p0.x, p0.y, p0.z, p0.w, p1.x, p1.y, p1.z, p1.w};
      float hh[4] = {hv.x, hv.y, hv.z, hv.w};
      #pragma unroll
      for (int ci = 0; ci < 4; ++ci)
        #pragma unroll
        for (int mj = 0; mj < 8; ++mj)
          acc[ci][mj] += hh[ci] * pv[mj];
    }
  }

  // reduce partial v across the 4 waves (scratch = Plds)
  __syncthreads();
  float* scratch = Plds;
  int base = (tid & 63) * 32;
  if (nh >= 2) {
    float* d = &scratch[(nh - 2) * 2048 + base];
    #pragma unroll
    for (int ci = 0; ci < 4; ++ci)
      #pragma unroll
      for (int mj = 0; mj < 8; ++mj) d[ci * 8 + mj] = acc[ci][mj];
  }
  __syncthreads();
  if (nh < 2) {
    const float* d = &scratch[nh * 2048 + base];
    #pragma unroll
    for (int ci = 0; ci < 4; ++ci)
      #pragma unroll
      for (int mj = 0; mj < 8; ++mj) acc[ci][mj] += d[ci * 8 + mj];
  }
  __syncthreads();
  if (nh == 1) {
    float* d = &scratch[base];
    #pragma unroll
    for (int ci = 0; ci < 4; ++ci)
      #pragma unroll
      for (int mj = 0; mj < 8; ++mj) d[ci * 8 + mj] = acc[ci][mj];
  }
  __syncthreads();
  if (nh == 0) {
    const float* d = &scratch[base];
    #pragma unroll
    for (int ci = 0; ci < 4; ++ci)
      #pragma unroll
      for (int mj = 0; mj < 8; ++mj) {
        float v = acc[ci][mj] + d[ci * 8 + mj];
        vlds[(cg * 4 + ci) * 68 + mgr * 8 + mj] = v;
      }
  }
  __syncthreads();

  // cooperative coalesced store of v tile [32][64] -> out's v region
  {
    int k = tid >> 3, c8 = (tid & 7) * 8;
    float4 a = *(float4*)&vlds[k * 68 + c8];
    float4 b4 = *(float4*)&vlds[k * 68 + c8 + 4];
    float* vdst = sc + OBASE(b) + OFF_V + (size_t)k * NN + m0 + c8;
    *(float4*)&vdst[0] = a;
    *(float4*)&vdst[4] = b4;
  }
}

// ------- epilogue: out[b,co,m] = gamma * (wv @ v) + x  (reads own v tile only) --
__global__ __launch_bounds__(256) void epi_kernel(
    float* out, const float* __restrict__ x,
    const float* __restrict__ wvp, const float* __restrict__ gamma)
{
  __shared__ float vlds[CK * 68];
  int tid = threadIdx.x;
  int blk = blockIdx.x;                 // B * 64 = 512 blocks
  int b = blk >> 6;
  int m0 = (blk & 63) << 6;

  // load this block's v tile [32][64] from out's v region (disjoint from any
  // region another epi block writes: write set of block (b',m0') at co<32 is
  // exactly the v columns m0', so only THIS block touches [b, :, m0:m0+64]).
  {
    int k = tid >> 3, c8 = (tid & 7) * 8;
    const float* vsrc = out + OBASE(b) + OFF_V + (size_t)k * NN + m0 + c8;
    float4 a = *(const float4*)&vsrc[0];
    float4 b4 = *(const float4*)&vsrc[4];
    *(float4*)&vlds[k * 68 + c8] = a;
    *(float4*)&vlds[k * 68 + c8 + 4] = b4;
  }
  __syncthreads();

  const float g0 = gamma[0];
  int nh = tid >> 6, mi = tid & 63;
  #pragma unroll 1
  for (int jb = 0; jb < 4; ++jb) {
    float oacc[16];
    #pragma unroll
    for (int j = 0; j < 16; ++j) oacc[j] = 0.f;
    for (int k = 0; k < CK; ++k) {
      float vv = vlds[k * 68 + mi];
      #pragma unroll
      for (int j = 0; j < 16; ++j)
        oacc[j] += wvp[(nh * 64 + jb * 16 + j) * CK + k] * vv;  // uniform -> s_load
    }
    #pragma unroll
    for (int j = 0; j < 16; ++j) {
      int co = nh * 64 + jb * 16 + j;
      size_t idx = ((size_t)b * CC + co) * NN + m0 + mi;
      out[idx] = g0 * oacc[j] + x[idx];
    }
  }
}

extern "C" void kernel_launch(void* const* d_in, const int* in_sizes, int n_in,
                              void* d_out, int out_size, void* d_ws, size_t ws_size,
                              hipStream_t stream) {
  const float* x     = (const float*)d_in[0];
  const float* wf    = (const float*)d_in[1];
  const float* wg    = (const float*)d_in[2];
  const float* wh    = (const float*)d_in[3];
  const float* wv    = (const float*)d_in[4];
  const float* gamma = (const float*)d_in[5];
  float* out = (float*)d_out;

  proj_kernel <<<256, 384, 0, stream>>>(x, wf, wg, wh, out);
  passb_kernel<<<512, 256, 0, stream>>>(out);
  passc_kernel<<<512, 256, 0, stream>>>(out);
  epi_kernel  <<<512, 256, 0, stream>>>(out, x, wv, gamma);
}

// Round 4
// 275.052 us; speedup vs baseline: 2.4243x; 2.4243x over previous
//
#include <hip/hip_runtime.h>
#include <hip/hip_bf16.h>

#define BB 8
#define CC 256
#define CK 32
#define NN 4096

typedef short bf16x8 __attribute__((ext_vector_type(8)));   // 8 bf16 bit patterns
typedef float f32x4 __attribute__((ext_vector_type(4)));

#define MFMA(a, b, c) __builtin_amdgcn_mfma_f32_16x16x32_bf16((a), (b), (c), 0, 0, 0)

// Per-b scratch layout INSIDE d_out (each b owns 1048576 floats = CC*NN = 4 MB).
// Every region starts at a multiple of 4096 floats => column-aligned in out's
// [256][4096] view, so the epi per-column ownership argument stays valid.
//   f  : bf16 [4096][32]  float-offs      0 .. 65536    (out rows  0-15)
//   g  : bf16 [4096][32]             65536 .. 131072    (rows 16-31)
//   hT : bf16 [32][4096]            131072 .. 196608    (rows 32-47)
//   LE : f32  [4096]                196608 .. 200704    (row  48)
//   v0 : f32  [32][4096]            200704 .. 331776    (rows 49-80)
//   v1 : f32  [32][4096]            331776 .. 462848    (rows 81-112)
#define OBASE(b) ((size_t)(b) * 1048576)
#define OFF_F  0
#define OFF_G  65536
#define OFF_HT 131072
#define OFF_LE 196608
#define OFF_V0 200704
#define OFF_V1 331776

#define SHIFT 24.0f

static __device__ __forceinline__ unsigned pack_trunc(float lo, float hi) {
  unsigned ulo = __builtin_bit_cast(unsigned, lo);
  unsigned uhi = __builtin_bit_cast(unsigned, hi);
  return (uhi & 0xFFFF0000u) | (ulo >> 16);
}
static __device__ __forceinline__ unsigned pack_rne(float lo, float hi) {
  unsigned ulo = __builtin_bit_cast(unsigned, lo);
  unsigned uhi = __builtin_bit_cast(unsigned, hi);
  ulo += 0x7FFFu + ((ulo >> 16) & 1u);
  uhi += 0x7FFFu + ((uhi >> 16) & 1u);
  return (uhi & 0xFFFF0000u) | (ulo >> 16);
}

// ---------------- projections: f/g token-major bf16, h transposed bf16 --------
__global__ __launch_bounds__(384) void proj_kernel(
    const float* __restrict__ x, const float* __restrict__ wf,
    const float* __restrict__ wg, const float* __restrict__ wh,
    float* __restrict__ sc)
{
  int tid = threadIdx.x;
  int blk = blockIdx.x;                 // B * 32 = 256 blocks
  int b = blk >> 5;
  int n = ((blk & 31) << 7) + (tid & 127);
  int wsel = __builtin_amdgcn_readfirstlane(tid >> 7);   // 0:f 1:g 2:h
  const float* w = (wsel == 0) ? wf : ((wsel == 1) ? wg : wh);

  const float* xb = x + (size_t)b * CC * NN + n;
  float acc[CK];
  #pragma unroll
  for (int k = 0; k < CK; ++k) acc[k] = 0.f;

  #pragma unroll 4
  for (int c = 0; c < CC; ++c) {
    float xv = xb[(size_t)c * NN];      // coalesced over n
    #pragma unroll
    for (int k = 0; k < CK; ++k) acc[k] += w[k * CC + c] * xv;  // uniform -> s_load
  }

  if (wsel < 2) {                       // f or g: token-major bf16 rows (64 B)
    size_t off = (wsel == 0) ? OFF_F : OFF_G;
    unsigned u[16];
    #pragma unroll
    for (int i = 0; i < 16; ++i) u[i] = pack_rne(acc[2 * i], acc[2 * i + 1]);
    uint4* o = (uint4*)((char*)(sc + OBASE(b) + off) + (size_t)n * 64);
    #pragma unroll
    for (int j = 0; j < 4; ++j)
      o[j] = make_uint4(u[4 * j], u[4 * j + 1], u[4 * j + 2], u[4 * j + 3]);
  } else {                              // h: transposed [c][n] bf16
    unsigned short* o = (unsigned short*)((char*)(sc + OBASE(b) + OFF_HT));
    #pragma unroll
    for (int k = 0; k < CK; ++k) {
      unsigned ub = __builtin_bit_cast(unsigned, acc[k]);
      ub += 0x7FFFu + ((ub >> 16) & 1u);
      o[(size_t)k * NN + n] = (unsigned short)(ub >> 16);
    }
  }
}

// ------ pass B: LE[n] = 24 + log( sum_m exp(s[n,m]-24) ), MFMA s --------------
__global__ __launch_bounds__(256) void passb_kernel(float* __restrict__ sc)
{
  int tid = threadIdx.x;
  int blk = blockIdx.x;                 // B * 64 = 512 blocks
  int b = blk >> 6;
  int n0 = (blk & 63) << 6;
  int wave = tid >> 6, lane = tid & 63;
  int q = lane >> 4, c = lane & 15;

  const char* fb = (const char*)(sc + OBASE(b) + OFF_F);
  const char* gb = (const char*)(sc + OBASE(b) + OFF_G);

  // loop-invariant A fragment: f rows [n0 + wave*16 .. +16)
  bf16x8 fa = *(const bf16x8*)(fb + (size_t)(n0 + wave * 16 + c) * 64 + q * 16);

  float z0 = 0.f, z1 = 0.f, z2 = 0.f, z3 = 0.f;
  const f32x4 zero4 = {0.f, 0.f, 0.f, 0.f};

  for (int mt = 0; mt < NN; mt += 64) {
    #pragma unroll
    for (int j = 0; j < 4; ++j) {
      bf16x8 gB = *(const bf16x8*)(gb + (size_t)(mt + j * 16 + c) * 64 + q * 16);
      f32x4 s = MFMA(fa, gB, zero4);
      z0 += __expf(s[0] - SHIFT);
      z1 += __expf(s[1] - SHIFT);
      z2 += __expf(s[2] - SHIFT);
      z3 += __expf(s[3] - SHIFT);
    }
  }
  // butterfly sum over the 16 m-lanes (low 4 lane bits)
  #pragma unroll
  for (int d = 1; d < 16; d <<= 1) {
    z0 += __shfl_xor(z0, d);
    z1 += __shfl_xor(z1, d);
    z2 += __shfl_xor(z2, d);
    z3 += __shfl_xor(z3, d);
  }
  if (c == 0) {
    float* LE = sc + OBASE(b) + OFF_LE + n0 + wave * 16 + q * 4;
    LE[0] = SHIFT + __logf(z0);
    LE[1] = SHIFT + __logf(z1);
    LE[2] = SHIFT + __logf(z2);
    LE[3] = SHIFT + __logf(z3);
  }
}

// ------ pass C: v = hT @ exp(s - LE), MFMA both GEMMs, n-split 2 --------------
__global__ __launch_bounds__(256, 4) void passc_kernel(float* __restrict__ sc)
{
  __shared__ unsigned Pt[64 * 32];      // P^T tile, 64 rows x 128 B, XOR-swizzled
  __shared__ float Lsh[2048];

  int tid = threadIdx.x;
  int blk = blockIdx.x;                 // B * 64 mblocks * 2 nhalves = 1024
  int b = blk >> 7;
  int rest = blk & 127;
  int ns = rest >> 6;
  int m0 = (rest & 63) << 6;
  int nbase = ns << 11;                 // 0 or 2048
  int wave = tid >> 6, lane = tid & 63;
  int q = lane >> 4, c = lane & 15;

  const char* fb = (const char*)(sc + OBASE(b) + OFF_F);
  const char* gb = (const char*)(sc + OBASE(b) + OFF_G);
  const char* hb = (const char*)(sc + OBASE(b) + OFF_HT);
  const float* LE = sc + OBASE(b) + OFF_LE;

  for (int i = tid; i < 2048; i += 256) Lsh[i] = LE[nbase + i];
  __syncthreads();

  // loop-invariant B fragment: g rows (= s columns) [m0 + wave*16 .. +16)
  bf16x8 gB = *(const bf16x8*)(gb + (size_t)(m0 + wave * 16 + c) * 64 + q * 16);

  f32x4 vacc0 = {0.f, 0.f, 0.f, 0.f};
  f32x4 vacc1 = {0.f, 0.f, 0.f, 0.f};
  const f32x4 zero4 = {0.f, 0.f, 0.f, 0.f};

  int r = wave * 16 + c;                // this lane's P^T row (its m column)
  unsigned sw = (unsigned)(c & 7) << 4; // XOR swizzle within the 128 B row
  char* PtB = (char*)Pt + r * 128;

  for (int nt = 0; nt < 2048; nt += 64) {
    // ---- s tile: 4 MFMAs over the 4 n-subtiles
    f32x4 sa[4];
    #pragma unroll
    for (int sub = 0; sub < 4; ++sub) {
      bf16x8 fa = *(const bf16x8*)(fb + (size_t)(nbase + nt + sub * 16 + c) * 64 + q * 16);
      sa[sub] = MFMA(fa, gB, zero4);
    }
    // ---- P = exp(s - LE), pack bf16, transpose-store (wave-private rows)
    #pragma unroll
    for (int sub = 0; sub < 4; ++sub) {
      const f32x4 Lt = *(const f32x4*)&Lsh[nt + sub * 16 + q * 4];
      float p0 = __expf(sa[sub][0] - Lt[0]);
      float p1 = __expf(sa[sub][1] - Lt[1]);
      float p2 = __expf(sa[sub][2] - Lt[2]);
      float p3 = __expf(sa[sub][3] - Lt[3]);
      uint2 pk;
      pk.x = pack_trunc(p0, p1);
      pk.y = pack_trunc(p2, p3);
      *(uint2*)(PtB + (((unsigned)(sub * 32 + q * 8)) ^ sw)) = pk;
    }
    // ---- PV: v[c',m] += hT[c'][n] * P[n][m], 2 k-halves x 2 c-subtiles
    #pragma unroll
    for (int ks = 0; ks < 2; ++ks) {
      bf16x8 pb = *(const bf16x8*)(PtB + (((unsigned)(ks * 64 + q * 16)) ^ sw));
      bf16x8 ha0 = *(const bf16x8*)(hb + (size_t)c * (NN * 2)
                                       + (size_t)(nbase + nt + ks * 32 + q * 8) * 2);
      bf16x8 ha1 = *(const bf16x8*)(hb + (size_t)(16 + c) * (NN * 2)
                                       + (size_t)(nbase + nt + ks * 32 + q * 8) * 2);
      vacc0 = MFMA(ha0, pb, vacc0);
      vacc1 = MFMA(ha1, pb, vacc1);
    }
  }

  // store partial v (f32, c-major) to v0 or v1
  float* V = sc + OBASE(b) + (ns ? OFF_V1 : OFF_V0);
  #pragma unroll
  for (int rr = 0; rr < 4; ++rr) {
    V[(size_t)(q * 4 + rr) * NN + m0 + wave * 16 + c] = vacc0[rr];
    V[(size_t)(16 + q * 4 + rr) * NN + m0 + wave * 16 + c] = vacc1[rr];
  }
}

// ------- epilogue: out[b,co,m] = gamma * (wv @ (v0+v1)) + x -------------------
__global__ __launch_bounds__(256) void epi_kernel(
    float* out, const float* __restrict__ x,
    const float* __restrict__ wvp, const float* __restrict__ gamma)
{
  __shared__ float vlds[CK * 68];
  int tid = threadIdx.x;
  int blk = blockIdx.x;                 // B * 64 = 512 blocks
  int b = blk >> 6;
  int m0 = (blk & 63) << 6;

  // sum the two n-half partials; this block reads only columns [m0, m0+64)
  {
    int k = tid >> 3, c8 = (tid & 7) * 8;
    const float* v0 = out + OBASE(b) + OFF_V0 + (size_t)k * NN + m0 + c8;
    const float* v1 = out + OBASE(b) + OFF_V1 + (size_t)k * NN + m0 + c8;
    float4 a0 = *(const float4*)&v0[0];
    float4 a1 = *(const float4*)&v0[4];
    float4 b0 = *(const float4*)&v1[0];
    float4 b1 = *(const float4*)&v1[4];
    *(float4*)&vlds[k * 68 + c8]     = make_float4(a0.x + b0.x, a0.y + b0.y, a0.z + b0.z, a0.w + b0.w);
    *(float4*)&vlds[k * 68 + c8 + 4] = make_float4(a1.x + b1.x, a1.y + b1.y, a1.z + b1.z, a1.w + b1.w);
  }
  __syncthreads();

  const float g0 = gamma[0];
  int nh = tid >> 6, mi = tid & 63;
  #pragma unroll 1
  for (int jb = 0; jb < 4; ++jb) {
    float oacc[16];
    #pragma unroll
    for (int j = 0; j < 16; ++j) oacc[j] = 0.f;
    for (int k = 0; k < CK; ++k) {
      float vv = vlds[k * 68 + mi];
      #pragma unroll
      for (int j = 0; j < 16; ++j)
        oacc[j] += wvp[(nh * 64 + jb * 16 + j) * CK + k] * vv;  // uniform -> s_load
    }
    #pragma unroll
    for (int j = 0; j < 16; ++j) {
      int co = nh * 64 + jb * 16 + j;
      size_t idx = ((size_t)b * CC + co) * NN + m0 + mi;
      out[idx] = g0 * oacc[j] + x[idx];
    }
  }
}

extern "C" void kernel_launch(void* const* d_in, const int* in_sizes, int n_in,
                              void* d_out, int out_size, void* d_ws, size_t ws_size,
                              hipStream_t stream) {
  const float* x     = (const float*)d_in[0];
  const float* wf    = (const float*)d_in[1];
  const float* wg    = (const float*)d_in[2];
  const float* wh    = (const float*)d_in[3];
  const float* wv    = (const float*)d_in[4];
  const float* gamma = (const float*)d_in[5];
  float* out = (float*)d_out;

  proj_kernel <<<256,  384, 0, stream>>>(x, wf, wg, wh, out);
  passb_kernel<<<512,  256, 0, stream>>>(out);
  passc_kernel<<<1024, 256, 0, stream>>>(out);
  epi_kernel  <<<512,  256, 0, stream>>>(out, x, wv, gamma);
}

// Round 5
// 190.487 us; speedup vs baseline: 3.5005x; 1.4439x over previous
//
#include <hip/hip_runtime.h>
#include <hip/hip_bf16.h>

#define BB 8
#define CC 256
#define CK 32
#define NN 4096

typedef short bf16x8 __attribute__((ext_vector_type(8)));   // 8 bf16 bit patterns
typedef float f32x4 __attribute__((ext_vector_type(4)));

#define MFMA(a, b, c) __builtin_amdgcn_mfma_f32_16x16x32_bf16((a), (b), (c), 0, 0, 0)

// Per-b scratch layout INSIDE d_out (each b owns 1048576 floats = CC*NN).
// Every region starts at a multiple of 4096 floats => column-aligned in out's
// [256][4096] view, so the epi per-column ownership argument stays valid.
//   f   : bf16 [4096][32]       0 .. 65536
//   g   : bf16 [4096][32]   65536 .. 131072
//   hT  : bf16 [32][4096]  131072 .. 196608
//   LE  : f32  [4096]      196608 .. 200704
//   v0  : f32  [32][4096]  200704 .. 331776
//   v1  : f32  [32][4096]  331776 .. 462848
//   xbf : bf16 [4096][256] 524288 .. 786432   (token-major transposed x)
//   wbf : bf16 [3][32][256] 786432 .. 798720  (GLOBAL, lives in b=0 region)
#define OBASE(b) ((size_t)(b) * 1048576)
#define OFF_F  0
#define OFF_G  65536
#define OFF_HT 131072
#define OFF_LE 196608
#define OFF_V0 200704
#define OFF_V1 331776
#define OFF_XB 524288
#define OFF_WB 786432

#define SHIFT 24.0f

static __device__ __forceinline__ unsigned pack_trunc(float lo, float hi) {
  unsigned ulo = __builtin_bit_cast(unsigned, lo);
  unsigned uhi = __builtin_bit_cast(unsigned, hi);
  return (uhi & 0xFFFF0000u) | (ulo >> 16);
}
static __device__ __forceinline__ unsigned pack_rne(float lo, float hi) {
  unsigned ulo = __builtin_bit_cast(unsigned, lo);
  unsigned uhi = __builtin_bit_cast(unsigned, hi);
  ulo += 0x7FFFu + ((ulo >> 16) & 1u);
  uhi += 0x7FFFu + ((uhi >> 16) & 1u);
  return (uhi & 0xFFFF0000u) | (ulo >> 16);
}
static __device__ __forceinline__ unsigned short rne16(float v) {
  unsigned u = __builtin_bit_cast(unsigned, v);
  u += 0x7FFFu + ((u >> 16) & 1u);
  return (unsigned short)(u >> 16);
}

// ---- cvt: x [c][n] f32 -> xbf [n][c] bf16 (LDS transpose); W -> wbf bf16 ----
__global__ __launch_bounds__(256) void cvt_kernel(
    const float* __restrict__ x, const float* __restrict__ wf,
    const float* __restrict__ wg, const float* __restrict__ wh,
    float* __restrict__ sc)
{
  int blk = blockIdx.x;
  int tid = threadIdx.x;
  if (blk >= 2048) {                    // weights -> wbf [3][32][256]
    unsigned short* wb = (unsigned short*)(sc + OFF_WB);
    const float* srcs[3] = {wf, wg, wh};
    #pragma unroll 1
    for (int w = 0; w < 3; ++w) {
      const float* src = srcs[w];
      for (int e = tid; e < 8192; e += 256) wb[w * 8192 + e] = rne16(src[e]);
    }
    return;
  }
  __shared__ float t[64][69];
  int b = blk >> 8, r = blk & 255, nt = r >> 2, ct = r & 3;
  int n0 = nt << 6, c0 = ct << 6;
  const float* xb = x + ((size_t)b * CC + c0) * NN + n0;
  int ci0 = tid >> 4, j = (tid & 15) << 2;
  #pragma unroll
  for (int p = 0; p < 4; ++p) {
    int ci = p * 16 + ci0;
    float4 v = *(const float4*)&xb[(size_t)ci * NN + j];
    t[ci][j] = v.x; t[ci][j + 1] = v.y; t[ci][j + 2] = v.z; t[ci][j + 3] = v.w;
  }
  __syncthreads();
  int ni = tid >> 2, cq = (tid & 3) << 4;
  unsigned u[8];
  #pragma unroll
  for (int e = 0; e < 8; ++e)
    u[e] = pack_rne(t[cq + 2 * e][ni], t[cq + 2 * e + 1][ni]);
  unsigned short* xbf = (unsigned short*)(sc + OBASE(b) + OFF_XB);
  unsigned* dst = (unsigned*)(xbf + (size_t)(n0 + ni) * CC + c0 + cq);
  *(uint4*)dst       = make_uint4(u[0], u[1], u[2], u[3]);
  *(uint4*)(dst + 4) = make_uint4(u[4], u[5], u[6], u[7]);
}

// ---- projmm: f/g = (xbf @ W^T) token-major, hT = W @ x, all via MFMA --------
__global__ __launch_bounds__(256) void projmm_kernel(float* __restrict__ sc)
{
  int tid = threadIdx.x, blk = blockIdx.x;
  int b = blk >> 6, nblk = blk & 63;
  int w = tid >> 6, lane = tid & 63, q = lane >> 4, c = lane & 15;
  int nb = (nblk << 6) + (w << 4);      // this wave's 16 tokens

  const char* xB = (const char*)(sc + OBASE(b) + OFF_XB);
  const char* wB = (const char*)(sc + OFF_WB);

  const f32x4 z4 = {0.f, 0.f, 0.f, 0.f};
  f32x4 fa0 = z4, fa1 = z4, ga0 = z4, ga1 = z4, ha0 = z4, ha1 = z4;

  #pragma unroll
  for (int kc = 0; kc < 8; ++kc) {
    int ko = kc * 64 + q * 16;
    bf16x8 xa = *(const bf16x8*)(xB + (size_t)(nb + c) * 512 + ko);
    bf16x8 w0 = *(const bf16x8*)(wB + (size_t)c * 512 + ko);
    bf16x8 w1 = *(const bf16x8*)(wB + (size_t)(16 + c) * 512 + ko);
    bf16x8 w2 = *(const bf16x8*)(wB + 16384 + (size_t)c * 512 + ko);
    bf16x8 w3 = *(const bf16x8*)(wB + 16384 + (size_t)(16 + c) * 512 + ko);
    bf16x8 w4 = *(const bf16x8*)(wB + 32768 + (size_t)c * 512 + ko);
    bf16x8 w5 = *(const bf16x8*)(wB + 32768 + (size_t)(16 + c) * 512 + ko);
    fa0 = MFMA(xa, w0, fa0);  fa1 = MFMA(xa, w1, fa1);   // out[n][o]
    ga0 = MFMA(xa, w2, ga0);  ga1 = MFMA(xa, w3, ga1);   // out[n][o]
    ha0 = MFMA(w4, xa, ha0);  ha1 = MFMA(w5, xa, ha1);   // out[o][n]
  }

  unsigned short* fD = (unsigned short*)(sc + OBASE(b) + OFF_F);
  unsigned short* gD = (unsigned short*)(sc + OBASE(b) + OFF_G);
  unsigned short* hD = (unsigned short*)(sc + OBASE(b) + OFF_HT);
  #pragma unroll
  for (int r = 0; r < 4; ++r) {
    int n = nb + q * 4 + r;
    fD[(size_t)n * 32 + c]      = rne16(fa0[r]);
    fD[(size_t)n * 32 + 16 + c] = rne16(fa1[r]);
    gD[(size_t)n * 32 + c]      = rne16(ga0[r]);
    gD[(size_t)n * 32 + 16 + c] = rne16(ga1[r]);
    hD[(size_t)(q * 4 + r) * NN + nb + c]        = rne16(ha0[r]);
    hD[(size_t)(16 + q * 4 + r) * NN + nb + c]   = rne16(ha1[r]);
  }
}

// ---- pass B: LE[n] = 24 + log(sum_m exp(s-24)); 2n x 2m wave split ----------
__global__ __launch_bounds__(256) void passb_kernel(float* __restrict__ sc)
{
  __shared__ float Zsh[2][16][2];       // [nsub][row][mhalf]
  int tid = threadIdx.x, blk = blockIdx.x;
  int b = blk >> 7, nb0 = (blk & 127) << 5;   // 32 rows per block
  int w = tid >> 6, lane = tid & 63, q = lane >> 4, c = lane & 15;
  int nsub = w & 1, mh = w >> 1;

  const char* fb = (const char*)(sc + OBASE(b) + OFF_F);
  const char* gb = (const char*)(sc + OBASE(b) + OFF_G);

  bf16x8 fa = *(const bf16x8*)(fb + (size_t)(nb0 + nsub * 16 + c) * 64 + q * 16);
  const f32x4 z4 = {0.f, 0.f, 0.f, 0.f};
  float z0 = 0.f, z1 = 0.f, z2 = 0.f, z3 = 0.f;

  int mt0 = mh << 11;
  bf16x8 g0 = *(const bf16x8*)(gb + (size_t)(mt0 + 0  + c) * 64 + q * 16);
  bf16x8 g1 = *(const bf16x8*)(gb + (size_t)(mt0 + 16 + c) * 64 + q * 16);
  bf16x8 g2 = *(const bf16x8*)(gb + (size_t)(mt0 + 32 + c) * 64 + q * 16);
  bf16x8 g3 = *(const bf16x8*)(gb + (size_t)(mt0 + 48 + c) * 64 + q * 16);

  for (int mt = mt0; mt < mt0 + 2048; mt += 64) {
    int mtn = (mt + 64 < mt0 + 2048) ? mt + 64 : mt0;   // wrap-read: harmless
    bf16x8 n0 = *(const bf16x8*)(gb + (size_t)(mtn + 0  + c) * 64 + q * 16);
    bf16x8 n1 = *(const bf16x8*)(gb + (size_t)(mtn + 16 + c) * 64 + q * 16);
    bf16x8 n2 = *(const bf16x8*)(gb + (size_t)(mtn + 32 + c) * 64 + q * 16);
    bf16x8 n3 = *(const bf16x8*)(gb + (size_t)(mtn + 48 + c) * 64 + q * 16);
    f32x4 s;
    s = MFMA(fa, g0, z4);
    z0 += __expf(s[0] - SHIFT); z1 += __expf(s[1] - SHIFT);
    z2 += __expf(s[2] - SHIFT); z3 += __expf(s[3] - SHIFT);
    s = MFMA(fa, g1, z4);
    z0 += __expf(s[0] - SHIFT); z1 += __expf(s[1] - SHIFT);
    z2 += __expf(s[2] - SHIFT); z3 += __expf(s[3] - SHIFT);
    s = MFMA(fa, g2, z4);
    z0 += __expf(s[0] - SHIFT); z1 += __expf(s[1] - SHIFT);
    z2 += __expf(s[2] - SHIFT); z3 += __expf(s[3] - SHIFT);
    s = MFMA(fa, g3, z4);
    z0 += __expf(s[0] - SHIFT); z1 += __expf(s[1] - SHIFT);
    z2 += __expf(s[2] - SHIFT); z3 += __expf(s[3] - SHIFT);
    g0 = n0; g1 = n1; g2 = n2; g3 = n3;
  }
  #pragma unroll
  for (int d = 1; d < 16; d <<= 1) {    // sum over the 16 m-lanes
    z0 += __shfl_xor(z0, d);
    z1 += __shfl_xor(z1, d);
    z2 += __shfl_xor(z2, d);
    z3 += __shfl_xor(z3, d);
  }
  if (c == 0) {
    Zsh[nsub][q * 4 + 0][mh] = z0;
    Zsh[nsub][q * 4 + 1][mh] = z1;
    Zsh[nsub][q * 4 + 2][mh] = z2;
    Zsh[nsub][q * 4 + 3][mh] = z3;
  }
  __syncthreads();
  if (tid < 32) {
    int row = tid & 15, ns2 = tid >> 4;
    float Z = Zsh[ns2][row][0] + Zsh[ns2][row][1];
    sc[OBASE(b) + OFF_LE + nb0 + ns2 * 16 + row] = SHIFT + __logf(Z);
  }
}

// ---- pass C: v = hT @ exp(s - LE); 2 m-tiles/wave, pipelined loads ----------
__global__ __launch_bounds__(256, 2) void passc_kernel(float* __restrict__ sc)
{
  __shared__ unsigned Pt[128 * 32];     // P^T: 128 rows x 128 B, XOR-swizzled
  __shared__ float Lsh[2048];

  int tid = threadIdx.x, blk = blockIdx.x;
  int b = blk >> 6, rest = blk & 63;
  int ns = rest & 1, mblk = rest >> 1;
  int m0 = mblk << 7;                   // 128 m-cols per block
  int nbase = ns << 11;                 // n-half: 0 or 2048
  int w = tid >> 6, lane = tid & 63, q = lane >> 4, c = lane & 15;

  const char* fb = (const char*)(sc + OBASE(b) + OFF_F);
  const char* gb = (const char*)(sc + OBASE(b) + OFF_G);
  const char* hb = (const char*)(sc + OBASE(b) + OFF_HT);
  const float* LE = sc + OBASE(b) + OFF_LE;

  for (int i = tid; i < 2048; i += 256) Lsh[i] = LE[nbase + i];
  __syncthreads();

  bf16x8 gB0 = *(const bf16x8*)(gb + (size_t)(m0 + w * 16 + c) * 64 + q * 16);
  bf16x8 gB1 = *(const bf16x8*)(gb + (size_t)(m0 + 64 + w * 16 + c) * 64 + q * 16);

  const f32x4 z4 = {0.f, 0.f, 0.f, 0.f};
  f32x4 v00 = z4, v01 = z4, v10 = z4, v11 = z4;   // [csub][mtile]

  unsigned sw = (unsigned)(c & 7) << 4;
  char* Pt0 = (char*)Pt + (size_t)(w * 16 + c) * 128;
  char* Pt1 = (char*)Pt + (size_t)(64 + w * 16 + c) * 128;

  bf16x8 fc0 = *(const bf16x8*)(fb + (size_t)(nbase + 0  + c) * 64 + q * 16);
  bf16x8 fc1 = *(const bf16x8*)(fb + (size_t)(nbase + 16 + c) * 64 + q * 16);
  bf16x8 fc2 = *(const bf16x8*)(fb + (size_t)(nbase + 32 + c) * 64 + q * 16);
  bf16x8 fc3 = *(const bf16x8*)(fb + (size_t)(nbase + 48 + c) * 64 + q * 16);

  for (int nt = 0; nt < 2048; nt += 64) {
    // ha loads for current iter (fly under the s/exp phase)
    bf16x8 ha00 = *(const bf16x8*)(hb + (size_t)c * 8192        + (size_t)(nbase + nt + q * 8) * 2);
    bf16x8 ha01 = *(const bf16x8*)(hb + (size_t)c * 8192        + (size_t)(nbase + nt + 32 + q * 8) * 2);
    bf16x8 ha10 = *(const bf16x8*)(hb + (size_t)(16 + c) * 8192 + (size_t)(nbase + nt + q * 8) * 2);
    bf16x8 ha11 = *(const bf16x8*)(hb + (size_t)(16 + c) * 8192 + (size_t)(nbase + nt + 32 + q * 8) * 2);

    f32x4 sA0 = MFMA(fc0, gB0, z4), sB0 = MFMA(fc0, gB1, z4);
    f32x4 sA1 = MFMA(fc1, gB0, z4), sB1 = MFMA(fc1, gB1, z4);
    f32x4 sA2 = MFMA(fc2, gB0, z4), sB2 = MFMA(fc2, gB1, z4);
    f32x4 sA3 = MFMA(fc3, gB0, z4), sB3 = MFMA(fc3, gB1, z4);

    // prefetch next iter's f fragments
    int ntn = (nt + 64 < 2048) ? nt + 64 : 0;
    bf16x8 fn0 = *(const bf16x8*)(fb + (size_t)(nbase + ntn + 0  + c) * 64 + q * 16);
    bf16x8 fn1 = *(const bf16x8*)(fb + (size_t)(nbase + ntn + 16 + c) * 64 + q * 16);
    bf16x8 fn2 = *(const bf16x8*)(fb + (size_t)(nbase + ntn + 32 + c) * 64 + q * 16);
    bf16x8 fn3 = *(const bf16x8*)(fb + (size_t)(nbase + ntn + 48 + c) * 64 + q * 16);

    // P = exp(s - LE) -> bf16 -> transposed rows (wave-private, no barrier)
    #pragma unroll
    for (int sub = 0; sub < 4; ++sub) {
      f32x4 sA = (sub == 0) ? sA0 : (sub == 1) ? sA1 : (sub == 2) ? sA2 : sA3;
      f32x4 sB = (sub == 0) ? sB0 : (sub == 1) ? sB1 : (sub == 2) ? sB2 : sB3;
      const f32x4 Lt = *(const f32x4*)&Lsh[nt + sub * 16 + q * 4];
      uint2 pkA, pkB;
      pkA.x = pack_trunc(__expf(sA[0] - Lt[0]), __expf(sA[1] - Lt[1]));
      pkA.y = pack_trunc(__expf(sA[2] - Lt[2]), __expf(sA[3] - Lt[3]));
      pkB.x = pack_trunc(__expf(sB[0] - Lt[0]), __expf(sB[1] - Lt[1]));
      pkB.y = pack_trunc(__expf(sB[2] - Lt[2]), __expf(sB[3] - Lt[3]));
      unsigned off = ((unsigned)(sub * 32 + q * 8)) ^ sw;
      *(uint2*)(Pt0 + off) = pkA;
      *(uint2*)(Pt1 + off) = pkB;
    }

    // PV
    #pragma unroll
    for (int ks = 0; ks < 2; ++ks) {
      unsigned off = ((unsigned)(ks * 64 + q * 16)) ^ sw;
      bf16x8 pb0 = *(const bf16x8*)(Pt0 + off);
      bf16x8 pb1 = *(const bf16x8*)(Pt1 + off);
      bf16x8 h0 = ks ? ha01 : ha00;
      bf16x8 h1 = ks ? ha11 : ha10;
      v00 = MFMA(h0, pb0, v00);
      v10 = MFMA(h1, pb0, v10);
      v01 = MFMA(h0, pb1, v01);
      v11 = MFMA(h1, pb1, v11);
    }
    fc0 = fn0; fc1 = fn1; fc2 = fn2; fc3 = fn3;
  }

  float* V = sc + OBASE(b) + (ns ? OFF_V1 : OFF_V0);
  #pragma unroll
  for (int r = 0; r < 4; ++r) {
    int mA = m0 + w * 16 + c, mB = m0 + 64 + w * 16 + c;
    V[(size_t)(q * 4 + r) * NN + mA]      = v00[r];
    V[(size_t)(16 + q * 4 + r) * NN + mA] = v10[r];
    V[(size_t)(q * 4 + r) * NN + mB]      = v01[r];
    V[(size_t)(16 + q * 4 + r) * NN + mB] = v11[r];
  }
}

// ------- epilogue: out[b,co,m] = gamma * (wv @ (v0+v1)) + x -------------------
__global__ __launch_bounds__(256) void epi_kernel(
    float* out, const float* __restrict__ x,
    const float* __restrict__ wvp, const float* __restrict__ gamma)
{
  __shared__ float vlds[CK * 68];
  int tid = threadIdx.x;
  int blk = blockIdx.x;                 // B * 64 = 512 blocks
  int b = blk >> 6;
  int m0 = (blk & 63) << 6;

  {
    int k = tid >> 3, c8 = (tid & 7) * 8;
    const float* v0 = out + OBASE(b) + OFF_V0 + (size_t)k * NN + m0 + c8;
    const float* v1 = out + OBASE(b) + OFF_V1 + (size_t)k * NN + m0 + c8;
    float4 a0 = *(const float4*)&v0[0];
    float4 a1 = *(const float4*)&v0[4];
    float4 b0 = *(const float4*)&v1[0];
    float4 b1 = *(const float4*)&v1[4];
    *(float4*)&vlds[k * 68 + c8]     = make_float4(a0.x + b0.x, a0.y + b0.y, a0.z + b0.z, a0.w + b0.w);
    *(float4*)&vlds[k * 68 + c8 + 4] = make_float4(a1.x + b1.x, a1.y + b1.y, a1.z + b1.z, a1.w + b1.w);
  }
  __syncthreads();

  const float g0 = gamma[0];
  int nh = tid >> 6, mi = tid & 63;
  #pragma unroll 1
  for (int jb = 0; jb < 4; ++jb) {
    float oacc[16];
    #pragma unroll
    for (int j = 0; j < 16; ++j) oacc[j] = 0.f;
    for (int k = 0; k < CK; ++k) {
      float vv = vlds[k * 68 + mi];
      #pragma unroll
      for (int j = 0; j < 16; ++j)
        oacc[j] += wvp[(nh * 64 + jb * 16 + j) * CK + k] * vv;  // uniform -> s_load
    }
    #pragma unroll
    for (int j = 0; j < 16; ++j) {
      int co = nh * 64 + jb * 16 + j;
      size_t idx = ((size_t)b * CC + co) * NN + m0 + mi;
      out[idx] = g0 * oacc[j] + x[idx];
    }
  }
}

extern "C" void kernel_launch(void* const* d_in, const int* in_sizes, int n_in,
                              void* d_out, int out_size, void* d_ws, size_t ws_size,
                              hipStream_t stream) {
  const float* x     = (const float*)d_in[0];
  const float* wf    = (const float*)d_in[1];
  const float* wg    = (const float*)d_in[2];
  const float* wh    = (const float*)d_in[3];
  const float* wv    = (const float*)d_in[4];
  const float* gamma = (const float*)d_in[5];
  float* out = (float*)d_out;

  cvt_kernel   <<<2049, 256, 0, stream>>>(x, wf, wg, wh, out);
  projmm_kernel<<<512,  256, 0, stream>>>(out);
  passb_kernel <<<1024, 256, 0, stream>>>(out);
  passc_kernel <<<512,  256, 0, stream>>>(out);
  epi_kernel   <<<512,  256, 0, stream>>>(out, x, wv, gamma);
}

// Round 6
// 141.946 us; speedup vs baseline: 4.6975x; 1.3420x over previous
//
#include <hip/hip_runtime.h>
#include <hip/hip_bf16.h>

#define BB 8
#define CC 256
#define CK 32
#define NN 4096

typedef short bf16x8 __attribute__((ext_vector_type(8)));   // 8 bf16 bit patterns
typedef float f32x4 __attribute__((ext_vector_type(4)));

#define MFMA(a, b, c) __builtin_amdgcn_mfma_f32_16x16x32_bf16((a), (b), (c), 0, 0, 0)

// Per-b scratch layout INSIDE d_out (each b owns 1048576 floats = CC*NN).
// f/g/hT/LE/xbf/wbf regions start at multiples of 4096 floats (column-aligned
// in out's [256][4096] view). v0/v1 use a per-m-block 32x32 tile layout that
// keeps each tile inside the COLUMNS its m-block owns:
//   addr(m, k) = OFF_V + (m & 31) * 4096 + (m >> 5) * 32 + k
// so epi block (b, m0) reads only columns [m0, m0+32) — the columns it alone
// writes. Cross-block race-freedom preserved.
//   f   : bf16 [4096][32]       0 .. 65536
//   g   : bf16 [4096][32]   65536 .. 131072
//   hT  : bf16 [32][4096]  131072 .. 196608
//   LE  : f32  [4096]      196608 .. 200704
//   v0  : f32  tiles       200704 .. 331776   (rows 49-81)
//   v1  : f32  tiles       331776 .. 462848   (rows 81-113)
//   xbf : bf16 [4096][256] 524288 .. 786432
//   wbf : bf16 [3][32][256] 786432 .. 798720  (GLOBAL, in b=0 region)
#define OBASE(b) ((size_t)(b) * 1048576)
#define OFF_F  0
#define OFF_G  65536
#define OFF_HT 131072
#define OFF_LE 196608
#define OFF_V0 200704
#define OFF_V1 331776
#define OFF_XB 524288
#define OFF_WB 786432

#define SHIFT 24.0f

static __device__ __forceinline__ unsigned pack_trunc(float lo, float hi) {
  unsigned ulo = __builtin_bit_cast(unsigned, lo);
  unsigned uhi = __builtin_bit_cast(unsigned, hi);
  return (uhi & 0xFFFF0000u) | (ulo >> 16);
}
static __device__ __forceinline__ unsigned pack_rne(float lo, float hi) {
  unsigned ulo = __builtin_bit_cast(unsigned, lo);
  unsigned uhi = __builtin_bit_cast(unsigned, hi);
  ulo += 0x7FFFu + ((ulo >> 16) & 1u);
  uhi += 0x7FFFu + ((uhi >> 16) & 1u);
  return (uhi & 0xFFFF0000u) | (ulo >> 16);
}
static __device__ __forceinline__ unsigned short rne16(float v) {
  unsigned u = __builtin_bit_cast(unsigned, v);
  u += 0x7FFFu + ((u >> 16) & 1u);
  return (unsigned short)(u >> 16);
}

// ---- cvt: x [c][n] f32 -> xbf [n][c] bf16 (LDS transpose); W -> wbf bf16 ----
__global__ __launch_bounds__(256) void cvt_kernel(
    const float* __restrict__ x, const float* __restrict__ wf,
    const float* __restrict__ wg, const float* __restrict__ wh,
    float* __restrict__ sc)
{
  int blk = blockIdx.x;
  int tid = threadIdx.x;
  if (blk >= 2048) {                    // weights -> wbf [3][32][256]
    unsigned short* wb = (unsigned short*)(sc + OFF_WB);
    const float* srcs[3] = {wf, wg, wh};
    #pragma unroll 1
    for (int w = 0; w < 3; ++w) {
      const float* src = srcs[w];
      for (int e = tid; e < 8192; e += 256) wb[w * 8192 + e] = rne16(src[e]);
    }
    return;
  }
  __shared__ float t[64][69];
  int b = blk >> 8, r = blk & 255, nt = r >> 2, ct = r & 3;
  int n0 = nt << 6, c0 = ct << 6;
  const float* xb = x + ((size_t)b * CC + c0) * NN + n0;
  int ci0 = tid >> 4, j = (tid & 15) << 2;
  #pragma unroll
  for (int p = 0; p < 4; ++p) {
    int ci = p * 16 + ci0;
    float4 v = *(const float4*)&xb[(size_t)ci * NN + j];
    t[ci][j] = v.x; t[ci][j + 1] = v.y; t[ci][j + 2] = v.z; t[ci][j + 3] = v.w;
  }
  __syncthreads();
  int ni = tid >> 2, cq = (tid & 3) << 4;
  unsigned u[8];
  #pragma unroll
  for (int e = 0; e < 8; ++e)
    u[e] = pack_rne(t[cq + 2 * e][ni], t[cq + 2 * e + 1][ni]);
  unsigned short* xbf = (unsigned short*)(sc + OBASE(b) + OFF_XB);
  unsigned* dst = (unsigned*)(xbf + (size_t)(n0 + ni) * CC + c0 + cq);
  *(uint4*)dst       = make_uint4(u[0], u[1], u[2], u[3]);
  *(uint4*)(dst + 4) = make_uint4(u[4], u[5], u[6], u[7]);
}

// ---- projmm: f/g = (xbf @ W^T) token-major, hT = W @ x, all via MFMA --------
__global__ __launch_bounds__(256) void projmm_kernel(float* __restrict__ sc)
{
  int tid = threadIdx.x, blk = blockIdx.x;
  int b = blk >> 6, nblk = blk & 63;
  int w = tid >> 6, lane = tid & 63, q = lane >> 4, c = lane & 15;
  int nb = (nblk << 6) + (w << 4);      // this wave's 16 tokens

  const char* xB = (const char*)(sc + OBASE(b) + OFF_XB);
  const char* wB = (const char*)(sc + OFF_WB);

  const f32x4 z4 = {0.f, 0.f, 0.f, 0.f};
  f32x4 fa0 = z4, fa1 = z4, ga0 = z4, ga1 = z4, ha0 = z4, ha1 = z4;

  #pragma unroll
  for (int kc = 0; kc < 8; ++kc) {
    int ko = kc * 64 + q * 16;
    bf16x8 xa = *(const bf16x8*)(xB + (size_t)(nb + c) * 512 + ko);
    bf16x8 w0 = *(const bf16x8*)(wB + (size_t)c * 512 + ko);
    bf16x8 w1 = *(const bf16x8*)(wB + (size_t)(16 + c) * 512 + ko);
    bf16x8 w2 = *(const bf16x8*)(wB + 16384 + (size_t)c * 512 + ko);
    bf16x8 w3 = *(const bf16x8*)(wB + 16384 + (size_t)(16 + c) * 512 + ko);
    bf16x8 w4 = *(const bf16x8*)(wB + 32768 + (size_t)c * 512 + ko);
    bf16x8 w5 = *(const bf16x8*)(wB + 32768 + (size_t)(16 + c) * 512 + ko);
    fa0 = MFMA(xa, w0, fa0);  fa1 = MFMA(xa, w1, fa1);   // out[n][o]
    ga0 = MFMA(xa, w2, ga0);  ga1 = MFMA(xa, w3, ga1);   // out[n][o]
    ha0 = MFMA(w4, xa, ha0);  ha1 = MFMA(w5, xa, ha1);   // out[o][n]
  }

  unsigned short* fD = (unsigned short*)(sc + OBASE(b) + OFF_F);
  unsigned short* gD = (unsigned short*)(sc + OBASE(b) + OFF_G);
  unsigned short* hD = (unsigned short*)(sc + OBASE(b) + OFF_HT);
  #pragma unroll
  for (int r = 0; r < 4; ++r) {
    int n = nb + q * 4 + r;
    fD[(size_t)n * 32 + c]      = rne16(fa0[r]);
    fD[(size_t)n * 32 + 16 + c] = rne16(fa1[r]);
    gD[(size_t)n * 32 + c]      = rne16(ga0[r]);
    gD[(size_t)n * 32 + 16 + c] = rne16(ga1[r]);
    hD[(size_t)(q * 4 + r) * NN + nb + c]        = rne16(ha0[r]);
    hD[(size_t)(16 + q * 4 + r) * NN + nb + c]   = rne16(ha1[r]);
  }
}

// ---- pass B: LE[n] = 24 + log(sum_m exp(s-24)); 2n x 2m wave split ----------
__global__ __launch_bounds__(256) void passb_kernel(float* __restrict__ sc)
{
  __shared__ float Zsh[2][16][2];       // [nsub][row][mhalf]
  int tid = threadIdx.x, blk = blockIdx.x;
  int b = blk >> 7, nb0 = (blk & 127) << 5;   // 32 rows per block
  int w = tid >> 6, lane = tid & 63, q = lane >> 4, c = lane & 15;
  int nsub = w & 1, mh = w >> 1;

  const char* fb = (const char*)(sc + OBASE(b) + OFF_F);
  const char* gb = (const char*)(sc + OBASE(b) + OFF_G);

  bf16x8 fa = *(const bf16x8*)(fb + (size_t)(nb0 + nsub * 16 + c) * 64 + q * 16);
  const f32x4 z4 = {0.f, 0.f, 0.f, 0.f};
  float z0 = 0.f, z1 = 0.f, z2 = 0.f, z3 = 0.f;

  int mt0 = mh << 11;
  bf16x8 g0 = *(const bf16x8*)(gb + (size_t)(mt0 + 0  + c) * 64 + q * 16);
  bf16x8 g1 = *(const bf16x8*)(gb + (size_t)(mt0 + 16 + c) * 64 + q * 16);
  bf16x8 g2 = *(const bf16x8*)(gb + (size_t)(mt0 + 32 + c) * 64 + q * 16);
  bf16x8 g3 = *(const bf16x8*)(gb + (size_t)(mt0 + 48 + c) * 64 + q * 16);

  for (int mt = mt0; mt < mt0 + 2048; mt += 64) {
    int mtn = (mt + 64 < mt0 + 2048) ? mt + 64 : mt0;   // wrap-read: harmless
    bf16x8 n0 = *(const bf16x8*)(gb + (size_t)(mtn + 0  + c) * 64 + q * 16);
    bf16x8 n1 = *(const bf16x8*)(gb + (size_t)(mtn + 16 + c) * 64 + q * 16);
    bf16x8 n2 = *(const bf16x8*)(gb + (size_t)(mtn + 32 + c) * 64 + q * 16);
    bf16x8 n3 = *(const bf16x8*)(gb + (size_t)(mtn + 48 + c) * 64 + q * 16);
    f32x4 s;
    s = MFMA(fa, g0, z4);
    z0 += __expf(s[0] - SHIFT); z1 += __expf(s[1] - SHIFT);
    z2 += __expf(s[2] - SHIFT); z3 += __expf(s[3] - SHIFT);
    s = MFMA(fa, g1, z4);
    z0 += __expf(s[0] - SHIFT); z1 += __expf(s[1] - SHIFT);
    z2 += __expf(s[2] - SHIFT); z3 += __expf(s[3] - SHIFT);
    s = MFMA(fa, g2, z4);
    z0 += __expf(s[0] - SHIFT); z1 += __expf(s[1] - SHIFT);
    z2 += __expf(s[2] - SHIFT); z3 += __expf(s[3] - SHIFT);
    s = MFMA(fa, g3, z4);
    z0 += __expf(s[0] - SHIFT); z1 += __expf(s[1] - SHIFT);
    z2 += __expf(s[2] - SHIFT); z3 += __expf(s[3] - SHIFT);
    g0 = n0; g1 = n1; g2 = n2; g3 = n3;
  }
  #pragma unroll
  for (int d = 1; d < 16; d <<= 1) {    // sum over the 16 m-lanes
    z0 += __shfl_xor(z0, d);
    z1 += __shfl_xor(z1, d);
    z2 += __shfl_xor(z2, d);
    z3 += __shfl_xor(z3, d);
  }
  if (c == 0) {
    Zsh[nsub][q * 4 + 0][mh] = z0;
    Zsh[nsub][q * 4 + 1][mh] = z1;
    Zsh[nsub][q * 4 + 2][mh] = z2;
    Zsh[nsub][q * 4 + 3][mh] = z3;
  }
  __syncthreads();
  if (tid < 32) {
    int row = tid & 15, ns2 = tid >> 4;
    float Z = Zsh[ns2][row][0] + Zsh[ns2][row][1];
    sc[OBASE(b) + OFF_LE + nb0 + ns2 * 16 + row] = SHIFT + __logf(Z);
  }
}

// ---- pass C: v = hT @ exp(s - LE); 2 m-tiles/wave, pipelined loads ----------
__global__ __launch_bounds__(256, 2) void passc_kernel(float* __restrict__ sc)
{
  __shared__ unsigned Pt[128 * 32];     // P^T: 128 rows x 128 B, XOR-swizzled
  __shared__ float Lsh[2048];

  int tid = threadIdx.x, blk = blockIdx.x;
  int b = blk >> 6, rest = blk & 63;
  int ns = rest & 1, mblk = rest >> 1;
  int m0 = mblk << 7;                   // 128 m-cols per block
  int nbase = ns << 11;                 // n-half: 0 or 2048
  int w = tid >> 6, lane = tid & 63, q = lane >> 4, c = lane & 15;

  const char* fb = (const char*)(sc + OBASE(b) + OFF_F);
  const char* gb = (const char*)(sc + OBASE(b) + OFF_G);
  const char* hb = (const char*)(sc + OBASE(b) + OFF_HT);
  const float* LE = sc + OBASE(b) + OFF_LE;

  for (int i = tid; i < 2048; i += 256) Lsh[i] = LE[nbase + i];
  __syncthreads();

  bf16x8 gB0 = *(const bf16x8*)(gb + (size_t)(m0 + w * 16 + c) * 64 + q * 16);
  bf16x8 gB1 = *(const bf16x8*)(gb + (size_t)(m0 + 64 + w * 16 + c) * 64 + q * 16);

  const f32x4 z4 = {0.f, 0.f, 0.f, 0.f};
  f32x4 v00 = z4, v01 = z4, v10 = z4, v11 = z4;   // [csub][mtile]

  unsigned sw = (unsigned)(c & 7) << 4;
  char* Pt0 = (char*)Pt + (size_t)(w * 16 + c) * 128;
  char* Pt1 = (char*)Pt + (size_t)(64 + w * 16 + c) * 128;

  bf16x8 fc0 = *(const bf16x8*)(fb + (size_t)(nbase + 0  + c) * 64 + q * 16);
  bf16x8 fc1 = *(const bf16x8*)(fb + (size_t)(nbase + 16 + c) * 64 + q * 16);
  bf16x8 fc2 = *(const bf16x8*)(fb + (size_t)(nbase + 32 + c) * 64 + q * 16);
  bf16x8 fc3 = *(const bf16x8*)(fb + (size_t)(nbase + 48 + c) * 64 + q * 16);

  for (int nt = 0; nt < 2048; nt += 64) {
    // ha loads for current iter (fly under the s/exp phase)
    bf16x8 ha00 = *(const bf16x8*)(hb + (size_t)c * 8192        + (size_t)(nbase + nt + q * 8) * 2);
    bf16x8 ha01 = *(const bf16x8*)(hb + (size_t)c * 8192        + (size_t)(nbase + nt + 32 + q * 8) * 2);
    bf16x8 ha10 = *(const bf16x8*)(hb + (size_t)(16 + c) * 8192 + (size_t)(nbase + nt + q * 8) * 2);
    bf16x8 ha11 = *(const bf16x8*)(hb + (size_t)(16 + c) * 8192 + (size_t)(nbase + nt + 32 + q * 8) * 2);

    f32x4 sA0 = MFMA(fc0, gB0, z4), sB0 = MFMA(fc0, gB1, z4);
    f32x4 sA1 = MFMA(fc1, gB0, z4), sB1 = MFMA(fc1, gB1, z4);
    f32x4 sA2 = MFMA(fc2, gB0, z4), sB2 = MFMA(fc2, gB1, z4);
    f32x4 sA3 = MFMA(fc3, gB0, z4), sB3 = MFMA(fc3, gB1, z4);

    // prefetch next iter's f fragments
    int ntn = (nt + 64 < 2048) ? nt + 64 : 0;
    bf16x8 fn0 = *(const bf16x8*)(fb + (size_t)(nbase + ntn + 0  + c) * 64 + q * 16);
    bf16x8 fn1 = *(const bf16x8*)(fb + (size_t)(nbase + ntn + 16 + c) * 64 + q * 16);
    bf16x8 fn2 = *(const bf16x8*)(fb + (size_t)(nbase + ntn + 32 + c) * 64 + q * 16);
    bf16x8 fn3 = *(const bf16x8*)(fb + (size_t)(nbase + ntn + 48 + c) * 64 + q * 16);

    // P = exp(s - LE) -> bf16 -> transposed rows (wave-private, no barrier)
    #pragma unroll
    for (int sub = 0; sub < 4; ++sub) {
      f32x4 sA = (sub == 0) ? sA0 : (sub == 1) ? sA1 : (sub == 2) ? sA2 : sA3;
      f32x4 sB = (sub == 0) ? sB0 : (sub == 1) ? sB1 : (sub == 2) ? sB2 : sB3;
      const f32x4 Lt = *(const f32x4*)&Lsh[nt + sub * 16 + q * 4];
      uint2 pkA, pkB;
      pkA.x = pack_trunc(__expf(sA[0] - Lt[0]), __expf(sA[1] - Lt[1]));
      pkA.y = pack_trunc(__expf(sA[2] - Lt[2]), __expf(sA[3] - Lt[3]));
      pkB.x = pack_trunc(__expf(sB[0] - Lt[0]), __expf(sB[1] - Lt[1]));
      pkB.y = pack_trunc(__expf(sB[2] - Lt[2]), __expf(sB[3] - Lt[3]));
      unsigned off = ((unsigned)(sub * 32 + q * 8)) ^ sw;
      *(uint2*)(Pt0 + off) = pkA;
      *(uint2*)(Pt1 + off) = pkB;
    }

    // PV
    #pragma unroll
    for (int ks = 0; ks < 2; ++ks) {
      unsigned off = ((unsigned)(ks * 64 + q * 16)) ^ sw;
      bf16x8 pb0 = *(const bf16x8*)(Pt0 + off);
      bf16x8 pb1 = *(const bf16x8*)(Pt1 + off);
      bf16x8 h0 = ks ? ha01 : ha00;
      bf16x8 h1 = ks ? ha11 : ha10;
      v00 = MFMA(h0, pb0, v00);
      v10 = MFMA(h1, pb0, v10);
      v01 = MFMA(h0, pb1, v01);
      v11 = MFMA(h1, pb1, v11);
    }
    fc0 = fn0; fc1 = fn1; fc2 = fn2; fc3 = fn3;
  }

  // store partial v in 32x32 per-m-block tiles: addr = (m&31)*4096+(m>>5)*32+k
  float* V = sc + OBASE(b) + (ns ? OFF_V1 : OFF_V0);
  {
    int mA = m0 + w * 16 + c, mB = m0 + 64 + w * 16 + c;
    size_t bA = (size_t)(mA & 31) * 4096 + (size_t)(mA >> 5) * 32;
    size_t bB = (size_t)(mB & 31) * 4096 + (size_t)(mB >> 5) * 32;
    *(f32x4*)&V[bA + q * 4]      = v00;
    *(f32x4*)&V[bA + 16 + q * 4] = v10;
    *(f32x4*)&V[bB + q * 4]      = v01;
    *(f32x4*)&V[bB + 16 + q * 4] = v11;
  }
}

// ------- epilogue: out[b,co,m] = gamma*(wv@(v0+v1)) + x, via MFMA ------------
__global__ __launch_bounds__(256) void epi_kernel(
    float* out, const float* __restrict__ x,
    const float* __restrict__ wv, const float* __restrict__ gamma)
{
  int tid = threadIdx.x, blk = blockIdx.x;   // B * 128 = 1024 blocks
  int b = blk >> 7;
  int m0 = (blk & 127) << 5;                 // 32 m-cols per block
  int w = tid >> 6, lane = tid & 63, q = lane >> 4, c = lane & 15;
  int co0 = w << 6;

  const float* V0 = out + OBASE(b) + OFF_V0;
  const float* V1 = out + OBASE(b) + OFF_V1;

  // B-frags: B[col=m][k q*8..+8] = (v0+v1)[m][k]; tile addr (m&31)*4096+(m>>5)*32+k
  bf16x8 Bf[2];
  #pragma unroll
  for (int mt = 0; mt < 2; ++mt) {
    int ml = mt * 16 + c;                    // m_local in [0,32)
    size_t base = (size_t)ml * 4096 + (size_t)(m0 >> 5) * 32 + q * 8;
    float4 a0 = *(const float4*)&V0[base];
    float4 a1 = *(const float4*)&V0[base + 4];
    float4 b0 = *(const float4*)&V1[base];
    float4 b1 = *(const float4*)&V1[base + 4];
    unsigned u0 = pack_rne(a0.x + b0.x, a0.y + b0.y);
    unsigned u1 = pack_rne(a0.z + b0.z, a0.w + b0.w);
    unsigned u2 = pack_rne(a1.x + b1.x, a1.y + b1.y);
    unsigned u3 = pack_rne(a1.z + b1.z, a1.w + b1.w);
    Bf[mt] = __builtin_bit_cast(bf16x8, make_uint4(u0, u1, u2, u3));
  }
  // A-frags: A[row=co][k] = wv[co][k] (f32 -> bf16 in-register)
  bf16x8 Af[4];
  #pragma unroll
  for (int ci = 0; ci < 4; ++ci) {
    const float* wr = wv + (size_t)(co0 + ci * 16 + c) * 32 + q * 8;
    float4 a0 = *(const float4*)wr;
    float4 a1 = *(const float4*)(wr + 4);
    unsigned u0 = pack_rne(a0.x, a0.y);
    unsigned u1 = pack_rne(a0.z, a0.w);
    unsigned u2 = pack_rne(a1.x, a1.y);
    unsigned u3 = pack_rne(a1.z, a1.w);
    Af[ci] = __builtin_bit_cast(bf16x8, make_uint4(u0, u1, u2, u3));
  }
  __syncthreads();   // all V reads done before any wave writes out rows 49-113

  const f32x4 z4 = {0.f, 0.f, 0.f, 0.f};
  const float g0 = gamma[0];
  #pragma unroll
  for (int ci = 0; ci < 4; ++ci) {
    #pragma unroll
    for (int mt = 0; mt < 2; ++mt) {
      f32x4 acc = MFMA(Af[ci], Bf[mt], z4);
      #pragma unroll
      for (int r = 0; r < 4; ++r) {
        int co = co0 + ci * 16 + q * 4 + r;
        size_t idx = ((size_t)b * CC + co) * NN + m0 + mt * 16 + c;
        out[idx] = g0 * acc[r] + x[idx];
      }
    }
  }
}

extern "C" void kernel_launch(void* const* d_in, const int* in_sizes, int n_in,
                              void* d_out, int out_size, void* d_ws, size_t ws_size,
                              hipStream_t stream) {
  const float* x     = (const float*)d_in[0];
  const float* wf    = (const float*)d_in[1];
  const float* wg    = (const float*)d_in[2];
  const float* wh    = (const float*)d_in[3];
  const float* wv    = (const float*)d_in[4];
  const float* gamma = (const float*)d_in[5];
  float* out = (float*)d_out;

  cvt_kernel   <<<2049, 256, 0, stream>>>(x, wf, wg, wh, out);
  projmm_kernel<<<512,  256, 0, stream>>>(out);
  passb_kernel <<<1024, 256, 0, stream>>>(out);
  passc_kernel <<<512,  256, 0, stream>>>(out);
  epi_kernel   <<<1024, 256, 0, stream>>>(out, x, wv, gamma);
}

// Round 7
// 120.586 us; speedup vs baseline: 5.5296x; 1.1771x over previous
//
#include <hip/hip_runtime.h>
#include <hip/hip_bf16.h>

#define BB 8
#define CC 256
#define CK 32
#define NN 4096

typedef short bf16x8 __attribute__((ext_vector_type(8)));   // 8 bf16 bit patterns
typedef float f32x4 __attribute__((ext_vector_type(4)));

#define MFMA(a, b, c) __builtin_amdgcn_mfma_f32_16x16x32_bf16((a), (b), (c), 0, 0, 0)

#define GLOAD16(gsrc, ldst) __builtin_amdgcn_global_load_lds( \
    (const __attribute__((address_space(1))) void*)(gsrc), \
    (__attribute__((address_space(3))) void*)(ldst), 16, 0, 0)

// Per-b scratch layout INSIDE d_out (each b owns 1048576 floats = CC*NN).
// f/g/hT/LE/xbf/wbf start at multiples of 4096 floats (column-aligned in
// out's [256][4096] view). v0..v3 use per-m-block 32x32 tiles:
//   addr(m,k) = OFF_Vi + (m & 31) * 4096 + (m >> 5) * 32 + k
// -> the tile for m-block mb occupies exactly columns [mb*32, mb*32+32),
// so epi block (b,m0) reads only the columns it alone writes. v2/v3 overlap
// the xbf region, which is dead after projmm.
//   f   : bf16 [4096][32]       0 .. 65536
//   g   : bf16 [4096][32]   65536 .. 131072
//   hT  : bf16 [32][4096]  131072 .. 196608
//   LE  : f32  [4096]      196608 .. 200704
//   v0..v3 : f32 tiles     200704 .. 724992
//   xbf : bf16 [4096][256] 524288 .. 786432   (dead after projmm)
//   wbf : bf16 [3][32][256] 786432 .. 798720  (GLOBAL, in b=0 region)
#define OBASE(b) ((size_t)(b) * 1048576)
#define OFF_F  0
#define OFF_G  65536
#define OFF_HT 131072
#define OFF_LE 196608
#define OFF_V0 200704
#define OFF_XB 524288
#define OFF_WB 786432
#define VSTRIDE 131072

#define SHIFT 24.0f

static __device__ __forceinline__ unsigned pack_trunc(float lo, float hi) {
  unsigned ulo = __builtin_bit_cast(unsigned, lo);
  unsigned uhi = __builtin_bit_cast(unsigned, hi);
  return (uhi & 0xFFFF0000u) | (ulo >> 16);
}
static __device__ __forceinline__ unsigned pack_rne(float lo, float hi) {
  unsigned ulo = __builtin_bit_cast(unsigned, lo);
  unsigned uhi = __builtin_bit_cast(unsigned, hi);
  ulo += 0x7FFFu + ((ulo >> 16) & 1u);
  uhi += 0x7FFFu + ((uhi >> 16) & 1u);
  return (uhi & 0xFFFF0000u) | (ulo >> 16);
}
static __device__ __forceinline__ unsigned short rne16(float v) {
  unsigned u = __builtin_bit_cast(unsigned, v);
  u += 0x7FFFu + ((u >> 16) & 1u);
  return (unsigned short)(u >> 16);
}

// ---- cvt: x [c][n] f32 -> xbf [n][c] bf16 (LDS transpose); W -> wbf bf16 ----
__global__ __launch_bounds__(256) void cvt_kernel(
    const float* __restrict__ x, const float* __restrict__ wf,
    const float* __restrict__ wg, const float* __restrict__ wh,
    float* __restrict__ sc)
{
  int blk = blockIdx.x;
  int tid = threadIdx.x;
  if (blk >= 2048) {                    // weights -> wbf [3][32][256]
    unsigned short* wb = (unsigned short*)(sc + OFF_WB);
    const float* srcs[3] = {wf, wg, wh};
    #pragma unroll 1
    for (int w = 0; w < 3; ++w) {
      const float* src = srcs[w];
      for (int e = tid; e < 8192; e += 256) wb[w * 8192 + e] = rne16(src[e]);
    }
    return;
  }
  __shared__ float t[64][69];
  int b = blk >> 8, r = blk & 255, nt = r >> 2, ct = r & 3;
  int n0 = nt << 6, c0 = ct << 6;
  const float* xb = x + ((size_t)b * CC + c0) * NN + n0;
  int ci0 = tid >> 4, j = (tid & 15) << 2;
  #pragma unroll
  for (int p = 0; p < 4; ++p) {
    int ci = p * 16 + ci0;
    float4 v = *(const float4*)&xb[(size_t)ci * NN + j];
    t[ci][j] = v.x; t[ci][j + 1] = v.y; t[ci][j + 2] = v.z; t[ci][j + 3] = v.w;
  }
  __syncthreads();
  int ni = tid >> 2, cq = (tid & 3) << 4;
  unsigned u[8];
  #pragma unroll
  for (int e = 0; e < 8; ++e)
    u[e] = pack_rne(t[cq + 2 * e][ni], t[cq + 2 * e + 1][ni]);
  unsigned short* xbf = (unsigned short*)(sc + OBASE(b) + OFF_XB);
  unsigned* dst = (unsigned*)(xbf + (size_t)(n0 + ni) * CC + c0 + cq);
  *(uint4*)dst       = make_uint4(u[0], u[1], u[2], u[3]);
  *(uint4*)(dst + 4) = make_uint4(u[4], u[5], u[6], u[7]);
}

// ---- projmm: f/g = (xbf @ W^T) token-major, hT = W @ x, all via MFMA --------
__global__ __launch_bounds__(256) void projmm_kernel(float* __restrict__ sc)
{
  int tid = threadIdx.x, blk = blockIdx.x;
  int b = blk >> 6, nblk = blk & 63;
  int w = tid >> 6, lane = tid & 63, q = lane >> 4, c = lane & 15;
  int nb = (nblk << 6) + (w << 4);      // this wave's 16 tokens

  const char* xB = (const char*)(sc + OBASE(b) + OFF_XB);
  const char* wB = (const char*)(sc + OFF_WB);

  const f32x4 z4 = {0.f, 0.f, 0.f, 0.f};
  f32x4 fa0 = z4, fa1 = z4, ga0 = z4, ga1 = z4, ha0 = z4, ha1 = z4;

  #pragma unroll
  for (int kc = 0; kc < 8; ++kc) {
    int ko = kc * 64 + q * 16;
    bf16x8 xa = *(const bf16x8*)(xB + (size_t)(nb + c) * 512 + ko);
    bf16x8 w0 = *(const bf16x8*)(wB + (size_t)c * 512 + ko);
    bf16x8 w1 = *(const bf16x8*)(wB + (size_t)(16 + c) * 512 + ko);
    bf16x8 w2 = *(const bf16x8*)(wB + 16384 + (size_t)c * 512 + ko);
    bf16x8 w3 = *(const bf16x8*)(wB + 16384 + (size_t)(16 + c) * 512 + ko);
    bf16x8 w4 = *(const bf16x8*)(wB + 32768 + (size_t)c * 512 + ko);
    bf16x8 w5 = *(const bf16x8*)(wB + 32768 + (size_t)(16 + c) * 512 + ko);
    fa0 = MFMA(xa, w0, fa0);  fa1 = MFMA(xa, w1, fa1);   // out[n][o]
    ga0 = MFMA(xa, w2, ga0);  ga1 = MFMA(xa, w3, ga1);   // out[n][o]
    ha0 = MFMA(w4, xa, ha0);  ha1 = MFMA(w5, xa, ha1);   // out[o][n]
  }

  unsigned short* fD = (unsigned short*)(sc + OBASE(b) + OFF_F);
  unsigned short* gD = (unsigned short*)(sc + OBASE(b) + OFF_G);
  unsigned short* hD = (unsigned short*)(sc + OBASE(b) + OFF_HT);
  #pragma unroll
  for (int r = 0; r < 4; ++r) {
    int n = nb + q * 4 + r;
    fD[(size_t)n * 32 + c]      = rne16(fa0[r]);
    fD[(size_t)n * 32 + 16 + c] = rne16(fa1[r]);
    gD[(size_t)n * 32 + c]      = rne16(ga0[r]);
    gD[(size_t)n * 32 + 16 + c] = rne16(ga1[r]);
    hD[(size_t)(q * 4 + r) * NN + nb + c]        = rne16(ha0[r]);
    hD[(size_t)(16 + q * 4 + r) * NN + nb + c]   = rne16(ha1[r]);
  }
}

// ---- pass B: LE[n] = 24 + log(sum_m exp(s-24)); 2 n-sub x 4 m-quarter ------
__global__ __launch_bounds__(256) void passb_kernel(float* __restrict__ sc)
{
  __shared__ float Zsh[2][16][4];       // [nsub][row][mquarter]
  int tid = threadIdx.x, blk = blockIdx.x;
  int b = blk >> 7, nb0 = (blk & 127) << 5;   // 32 rows per block
  int w = tid >> 6, lane = tid & 63, q = lane >> 4, c = lane & 15;

  const char* fb = (const char*)(sc + OBASE(b) + OFF_F);
  const char* gb = (const char*)(sc + OBASE(b) + OFF_G);

  bf16x8 fa0 = *(const bf16x8*)(fb + (size_t)(nb0 + c) * 64 + q * 16);
  bf16x8 fa1 = *(const bf16x8*)(fb + (size_t)(nb0 + 16 + c) * 64 + q * 16);
  const f32x4 z4 = {0.f, 0.f, 0.f, 0.f};
  float za[2][4] = {{0.f,0.f,0.f,0.f},{0.f,0.f,0.f,0.f}};

  int mt0 = w << 10;                    // this wave's 1024-m quarter
  bf16x8 g0 = *(const bf16x8*)(gb + (size_t)(mt0 + 0  + c) * 64 + q * 16);
  bf16x8 g1 = *(const bf16x8*)(gb + (size_t)(mt0 + 16 + c) * 64 + q * 16);
  bf16x8 g2 = *(const bf16x8*)(gb + (size_t)(mt0 + 32 + c) * 64 + q * 16);
  bf16x8 g3 = *(const bf16x8*)(gb + (size_t)(mt0 + 48 + c) * 64 + q * 16);

  for (int mt = mt0; mt < mt0 + 1024; mt += 64) {
    int mtn = (mt + 64 < mt0 + 1024) ? mt + 64 : mt0;   // wrap-read: harmless
    bf16x8 n0 = *(const bf16x8*)(gb + (size_t)(mtn + 0  + c) * 64 + q * 16);
    bf16x8 n1 = *(const bf16x8*)(gb + (size_t)(mtn + 16 + c) * 64 + q * 16);
    bf16x8 n2 = *(const bf16x8*)(gb + (size_t)(mtn + 32 + c) * 64 + q * 16);
    bf16x8 n3 = *(const bf16x8*)(gb + (size_t)(mtn + 48 + c) * 64 + q * 16);
    f32x4 s;
    #define BSTEP(gk) \
      s = MFMA(fa0, gk, z4); \
      za[0][0] += __expf(s[0] - SHIFT); za[0][1] += __expf(s[1] - SHIFT); \
      za[0][2] += __expf(s[2] - SHIFT); za[0][3] += __expf(s[3] - SHIFT); \
      s = MFMA(fa1, gk, z4); \
      za[1][0] += __expf(s[0] - SHIFT); za[1][1] += __expf(s[1] - SHIFT); \
      za[1][2] += __expf(s[2] - SHIFT); za[1][3] += __expf(s[3] - SHIFT);
    BSTEP(g0) BSTEP(g1) BSTEP(g2) BSTEP(g3)
    #undef BSTEP
    g0 = n0; g1 = n1; g2 = n2; g3 = n3;
  }
  #pragma unroll
  for (int d = 1; d < 16; d <<= 1) {    // sum over the 16 m-lanes
    #pragma unroll
    for (int i = 0; i < 2; ++i)
      #pragma unroll
      for (int r = 0; r < 4; ++r) za[i][r] += __shfl_xor(za[i][r], d);
  }
  if (c == 0) {
    #pragma unroll
    for (int i = 0; i < 2; ++i)
      #pragma unroll
      for (int r = 0; r < 4; ++r) Zsh[i][q * 4 + r][w] = za[i][r];
  }
  __syncthreads();
  if (tid < 32) {
    int ns2 = tid >> 4, row = tid & 15;
    float Z = Zsh[ns2][row][0] + Zsh[ns2][row][1]
            + Zsh[ns2][row][2] + Zsh[ns2][row][3];
    sc[OBASE(b) + OFF_LE + nb0 + ns2 * 16 + row] = SHIFT + __logf(Z);
  }
}

// ---- pass C: v = hT @ exp(s - LE); 4-way n split, LDS-staged f/h dbuf -------
__global__ __launch_bounds__(256, 4) void passc_kernel(float* __restrict__ sc)
{
  __shared__ unsigned Pt[128 * 32];     // P^T: 128 rows x 128 B, XOR-swizzled
  __shared__ float Lsh[1024];
  __shared__ unsigned fsh[2][1024];     // f tile [64 rows][64 B], dbuf
  __shared__ unsigned hsh[2][1024];     // h tile [32 rows][128 B], XOR-swizzled

  int tid = threadIdx.x, blk = blockIdx.x;
  int b = blk >> 7, rest = blk & 127;
  int ns = rest & 3, mblk = rest >> 2;
  int m0 = mblk << 7;                   // 128 m-cols per block
  int nbase = ns << 10;                 // n-quarter: 0,1024,2048,3072
  int w = tid >> 6, lane = tid & 63, q = lane >> 4, c = lane & 15;
  int hc = tid >> 3, hslot = (tid & 7) ^ (hc & 7);   // pre-swizzled h source

  const char* fb = (const char*)(sc + OBASE(b) + OFF_F);
  const char* gb = (const char*)(sc + OBASE(b) + OFF_G);
  const char* hb = (const char*)(sc + OBASE(b) + OFF_HT);
  const float* LE = sc + OBASE(b) + OFF_LE;

  for (int i = tid; i < 1024; i += 256) Lsh[i] = LE[nbase + i];

  bf16x8 gB0 = *(const bf16x8*)(gb + (size_t)(m0 + w * 16 + c) * 64 + q * 16);
  bf16x8 gB1 = *(const bf16x8*)(gb + (size_t)(m0 + 64 + w * 16 + c) * 64 + q * 16);

  // stage tile nt=0 into buf 0 (f linear; h with pre-swizzled source)
  GLOAD16(fb + (size_t)nbase * 64 + tid * 16, (char*)&fsh[0][0] + tid * 16);
  GLOAD16(hb + (size_t)hc * 8192 + (size_t)nbase * 2 + hslot * 16,
          (char*)&hsh[0][0] + tid * 16);
  __syncthreads();

  const f32x4 z4 = {0.f, 0.f, 0.f, 0.f};
  f32x4 v00 = z4, v01 = z4, v10 = z4, v11 = z4;   // [csub][mtile]

  unsigned sw = (unsigned)(c & 7) << 4;
  char* Pt0 = (char*)Pt + (size_t)(w * 16 + c) * 128;
  char* Pt1 = (char*)Pt + (size_t)(64 + w * 16 + c) * 128;

  int buf = 0;
  for (int nt = 0; nt < 1024; nt += 64) {
    // issue next tile's stage first (loads fly under this iter's compute)
    if (nt + 64 < 1024) {
      GLOAD16(fb + (size_t)(nbase + nt + 64) * 64 + tid * 16,
              (char*)&fsh[buf ^ 1][0] + tid * 16);
      GLOAD16(hb + (size_t)hc * 8192 + (size_t)(nbase + nt + 64) * 2 + hslot * 16,
              (char*)&hsh[buf ^ 1][0] + tid * 16);
    }
    const char* fS = (const char*)&fsh[buf][0];
    const char* hS = (const char*)&hsh[buf][0];

    // ---- s tiles from LDS f
    bf16x8 f0 = *(const bf16x8*)(fS + (0 * 16 + c) * 64 + q * 16);
    bf16x8 f1 = *(const bf16x8*)(fS + (1 * 16 + c) * 64 + q * 16);
    bf16x8 f2 = *(const bf16x8*)(fS + (2 * 16 + c) * 64 + q * 16);
    bf16x8 f3 = *(const bf16x8*)(fS + (3 * 16 + c) * 64 + q * 16);
    f32x4 sA0 = MFMA(f0, gB0, z4), sB0 = MFMA(f0, gB1, z4);
    f32x4 sA1 = MFMA(f1, gB0, z4), sB1 = MFMA(f1, gB1, z4);
    f32x4 sA2 = MFMA(f2, gB0, z4), sB2 = MFMA(f2, gB1, z4);
    f32x4 sA3 = MFMA(f3, gB0, z4), sB3 = MFMA(f3, gB1, z4);

    // ---- P = exp(s - LE) -> bf16 -> transposed rows (wave-private)
    #pragma unroll
    for (int sub = 0; sub < 4; ++sub) {
      f32x4 sA = (sub == 0) ? sA0 : (sub == 1) ? sA1 : (sub == 2) ? sA2 : sA3;
      f32x4 sB = (sub == 0) ? sB0 : (sub == 1) ? sB1 : (sub == 2) ? sB2 : sB3;
      const f32x4 Lt = *(const f32x4*)&Lsh[nt + sub * 16 + q * 4];
      uint2 pkA, pkB;
      pkA.x = pack_trunc(__expf(sA[0] - Lt[0]), __expf(sA[1] - Lt[1]));
      pkA.y = pack_trunc(__expf(sA[2] - Lt[2]), __expf(sA[3] - Lt[3]));
      pkB.x = pack_trunc(__expf(sB[0] - Lt[0]), __expf(sB[1] - Lt[1]));
      pkB.y = pack_trunc(__expf(sB[2] - Lt[2]), __expf(sB[3] - Lt[3]));
      unsigned off = ((unsigned)(sub * 32 + q * 8)) ^ sw;
      *(uint2*)(Pt0 + off) = pkA;
      *(uint2*)(Pt1 + off) = pkB;
    }

    // ---- PV from LDS h (XOR-swizzled rows) + Pt
    #pragma unroll
    for (int ks = 0; ks < 2; ++ks) {
      unsigned off = ((unsigned)(ks * 64 + q * 16)) ^ sw;
      bf16x8 pb0 = *(const bf16x8*)(Pt0 + off);
      bf16x8 pb1 = *(const bf16x8*)(Pt1 + off);
      unsigned hoff = ((unsigned)(ks * 64 + q * 16)) ^ sw;
      bf16x8 h0 = *(const bf16x8*)(hS + c * 128 + hoff);
      bf16x8 h1 = *(const bf16x8*)(hS + (16 + c) * 128 + hoff);
      v00 = MFMA(h0, pb0, v00);
      v10 = MFMA(h1, pb0, v10);
      v01 = MFMA(h0, pb1, v01);
      v11 = MFMA(h1, pb1, v11);
    }
    __syncthreads();                    // buf consumed by all; next stage done
    buf ^= 1;
  }

  // store partial v in 32x32 per-m-block tiles: addr = (m&31)*4096+(m>>5)*32+k
  float* V = sc + OBASE(b) + OFF_V0 + (size_t)ns * VSTRIDE;
  {
    int mA = m0 + w * 16 + c, mB = m0 + 64 + w * 16 + c;
    size_t bA = (size_t)(mA & 31) * 4096 + (size_t)(mA >> 5) * 32;
    size_t bB = (size_t)(mB & 31) * 4096 + (size_t)(mB >> 5) * 32;
    *(f32x4*)&V[bA + q * 4]      = v00;
    *(f32x4*)&V[bA + 16 + q * 4] = v10;
    *(f32x4*)&V[bB + q * 4]      = v01;
    *(f32x4*)&V[bB + 16 + q * 4] = v11;
  }
}

// ------- epilogue: out[b,co,m] = gamma*(wv@(v0+v1+v2+v3)) + x, via MFMA ------
__global__ __launch_bounds__(256) void epi_kernel(
    float* out, const float* __restrict__ x,
    const float* __restrict__ wv, const float* __restrict__ gamma)
{
  int tid = threadIdx.x, blk = blockIdx.x;   // B * 128 = 1024 blocks
  int b = blk >> 7;
  int m0 = (blk & 127) << 5;                 // 32 m-cols per block
  int w = tid >> 6, lane = tid & 63, q = lane >> 4, c = lane & 15;
  int co0 = w << 6;

  const float* V0 = out + OBASE(b) + OFF_V0;

  // B-frags: B[col=m][k] = sum_i vi[m][k]; tile addr (m&31)*4096+(m>>5)*32+k
  bf16x8 Bf[2];
  #pragma unroll
  for (int mt = 0; mt < 2; ++mt) {
    int ml = mt * 16 + c;                    // m_local in [0,32)
    size_t base = (size_t)ml * 4096 + (size_t)(m0 >> 5) * 32 + q * 8;
    float4 a0 = {0,0,0,0}, a1 = {0,0,0,0};
    #pragma unroll
    for (int i = 0; i < 4; ++i) {
      const float* Vi = V0 + (size_t)i * VSTRIDE;
      float4 p0 = *(const float4*)&Vi[base];
      float4 p1 = *(const float4*)&Vi[base + 4];
      a0.x += p0.x; a0.y += p0.y; a0.z += p0.z; a0.w += p0.w;
      a1.x += p1.x; a1.y += p1.y; a1.z += p1.z; a1.w += p1.w;
    }
    unsigned u0 = pack_rne(a0.x, a0.y);
    unsigned u1 = pack_rne(a0.z, a0.w);
    unsigned u2 = pack_rne(a1.x, a1.y);
    unsigned u3 = pack_rne(a1.z, a1.w);
    Bf[mt] = __builtin_bit_cast(bf16x8, make_uint4(u0, u1, u2, u3));
  }
  // A-frags: A[row=co][k] = wv[co][k] (f32 -> bf16 in-register)
  bf16x8 Af[4];
  #pragma unroll
  for (int ci = 0; ci < 4; ++ci) {
    const float* wr = wv + (size_t)(co0 + ci * 16 + c) * 32 + q * 8;
    float4 a0 = *(const float4*)wr;
    float4 a1 = *(const float4*)(wr + 4);
    unsigned u0 = pack_rne(a0.x, a0.y);
    unsigned u1 = pack_rne(a0.z, a0.w);
    unsigned u2 = pack_rne(a1.x, a1.y);
    unsigned u3 = pack_rne(a1.z, a1.w);
    Af[ci] = __builtin_bit_cast(bf16x8, make_uint4(u0, u1, u2, u3));
  }
  __syncthreads();   // all V reads done before any wave writes those rows

  const f32x4 z4 = {0.f, 0.f, 0.f, 0.f};
  const float g0 = gamma[0];
  #pragma unroll
  for (int ci = 0; ci < 4; ++ci) {
    #pragma unroll
    for (int mt = 0; mt < 2; ++mt) {
      f32x4 acc = MFMA(Af[ci], Bf[mt], z4);
      #pragma unroll
      for (int r = 0; r < 4; ++r) {
        int co = co0 + ci * 16 + q * 4 + r;
        size_t idx = ((size_t)b * CC + co) * NN + m0 + mt * 16 + c;
        out[idx] = g0 * acc[r] + x[idx];
      }
    }
  }
}

extern "C" void kernel_launch(void* const* d_in, const int* in_sizes, int n_in,
                              void* d_out, int out_size, void* d_ws, size_t ws_size,
                              hipStream_t stream) {
  const float* x     = (const float*)d_in[0];
  const float* wf    = (const float*)d_in[1];
  const float* wg    = (const float*)d_in[2];
  const float* wh    = (const float*)d_in[3];
  const float* wv    = (const float*)d_in[4];
  const float* gamma = (const float*)d_in[5];
  float* out = (float*)d_out;

  cvt_kernel   <<<2049, 256, 0, stream>>>(x, wf, wg, wh, out);
  projmm_kernel<<<512,  256, 0, stream>>>(out);
  passb_kernel <<<1024, 256, 0, stream>>>(out);
  passc_kernel <<<1024, 256, 0, stream>>>(out);
  epi_kernel   <<<1024, 256, 0, stream>>>(out, x, wv, gamma);
}